// Round 18
// baseline (63.507 us; speedup 1.0000x reference)
//
#include <hip/hip_runtime.h>
#include <stdint.h>

#define NTOK 8192
#define NCOL 4096     // DIM == VOCAB
#define RANK 256
#define TPB  64       // tokens per block (2 waves x 32 tokens)
#define CPB  256      // cols per block (16 col-tiles)

typedef __attribute__((ext_vector_type(8))) short bf16x8;
typedef __attribute__((ext_vector_type(4))) float f32x4;

__device__ __forceinline__ unsigned short f2bf(float f) {
    unsigned int u = __float_as_uint(f);
    u += 0x7fffu + ((u >> 16) & 1u);   // RNE
    return (unsigned short)(u >> 16);
}

// async global->LDS, 16B per lane; LDS dest = uniform base + lane*16 (m104)
__device__ __forceinline__ void gload_lds16(const uint4* g, uint4* l) {
    __builtin_amdgcn_global_load_lds(
        (const __attribute__((address_space(1))) void*)g,
        (__attribute__((address_space(3))) void*)l, 16, 0, 0);
}

// ---- combined pre-pass ----
// blocks [0, 1024): A fp32 [4096][256] -> bf16 row-major (Abf, 2 MiB, L2-resident)
// blocks [1024, 1536): B fp32 [256][4096] -> bf16 MFMA-B-fragment order
//   frag layout: flat uint4 index = (ct*8 + ks)*64 + lane, 8 bf16 each:
//     element j = B[ks*32 + (lane>>4)*8 + j][ct*16 + (lane&15)]
__global__ __launch_bounds__(256) void prep_kernel(
    const float* __restrict__ A, const float* __restrict__ B,
    unsigned short* __restrict__ Abf, unsigned short* __restrict__ Bfrag)
{
    if (blockIdx.x < 1024) {
        int i = blockIdx.x * 256 + threadIdx.x;
        float4 v = reinterpret_cast<const float4*>(A)[i];
        ushort4 o;
        o.x = f2bf(v.x); o.y = f2bf(v.y); o.z = f2bf(v.z); o.w = f2bf(v.w);
        reinterpret_cast<ushort4*>(Abf)[i] = o;
    } else {
        int gt = (blockIdx.x - 1024) * 256 + threadIdx.x;
        int ct = gt >> 9;
        int rem = gt & 511;
        int ks = rem >> 6;
        int ln = rem & 63;
        int col = ct * 16 + (ln & 15);
        int kb  = ks * 32 + ((ln >> 4) << 3);
        unsigned short pk[8];
        #pragma unroll
        for (int j = 0; j < 8; ++j)
            pk[j] = f2bf(B[(size_t)(kb + j) * NCOL + col]);
        uint4 o;
        o.x = (unsigned)pk[0] | ((unsigned)pk[1] << 16);
        o.y = (unsigned)pk[2] | ((unsigned)pk[3] << 16);
        o.z = (unsigned)pk[4] | ((unsigned)pk[5] << 16);
        o.w = (unsigned)pk[6] | ((unsigned)pk[7] << 16);
        reinterpret_cast<uint4*>(Bfrag)[gt] = o;
    }
}

// ---- main: fused gather + LoRA GEMM + W add + mask ----
// r15 schedule (LDS-staged B 2-buf, W-ring 4, counted vmcnt + raw barrier)
// re-cut into 128-thread / 2-wave blocks: same 16 waves/CU but 8 independent
// barrier-groups instead of 4 -> a stalled block's holes are filled by 7
// other blocks, and the tail quantum halves.
__global__ __launch_bounds__(128) void emb_lora_mfma(
    const int* __restrict__ x,
    const int* __restrict__ mask,
    const float* __restrict__ W,
    const unsigned short* __restrict__ Abf,
    const unsigned short* __restrict__ Bfrag,
    float* __restrict__ out)
{
    __shared__ int s_idx[TPB];
    __shared__ int s_msk[TPB];
    __shared__ uint4 b_lds[2][512];   // 2 x 8 KB (one B col-tile each)

    const int tid  = threadIdx.x;
    const int lane = tid & 63;
    const int wave = tid >> 6;        // 0/1: wave owns tokens [wave*32, +32)
    const int tok0 = blockIdx.x * TPB;
    const int col0 = blockIdx.y * CPB;

    if (tid < TPB) {
        s_idx[tid] = x[tok0 + tid];
        s_msk[tid] = mask[tok0 + tid];
    }
    __syncthreads();

    // A fragments for both token groups (A-operand row = lane&15)
    const int a0row = s_idx[wave * 32 + (lane & 15)];
    const int a1row = s_idx[wave * 32 + 16 + (lane & 15)];
    const unsigned short* ap0 = Abf + (size_t)a0row * RANK + ((lane >> 4) << 3);
    const unsigned short* ap1 = Abf + (size_t)a1row * RANK + ((lane >> 4) << 3);
    bf16x8 aA[8], aB[8];
    #pragma unroll
    for (int s = 0; s < 8; ++s) {
        aA[s] = *reinterpret_cast<const bf16x8*>(ap0 + s * 32);
        aB[s] = *reinterpret_cast<const bf16x8*>(ap1 + s * 32);
    }

    // per-thread epilogue state: group g covers rows wave*32+g*16+(lane>>4)*4+r
    const int colb = col0 + (lane & 15);
    int msk0[4], msk1[4];
    unsigned woff0[4], woff1[4], ooff0[4], ooff1[4];
    #pragma unroll
    for (int r = 0; r < 4; ++r) {
        int row0 = wave * 32 + ((lane >> 4) << 2) + r;
        int row1 = row0 + 16;
        msk0[r] = s_msk[row0];
        msk1[r] = s_msk[row1];
        woff0[r] = (unsigned)s_idx[row0] * NCOL + colb;
        woff1[r] = (unsigned)s_idx[row1] * NCOL + colb;
        ooff0[r] = (unsigned)(tok0 + row0) * NCOL + colb;
        ooff1[r] = (unsigned)(tok0 + row1) * NCOL + colb;
    }

    // block's 16 col-tiles start at global col-tile blockIdx.y*16
    const uint4* bpanel = reinterpret_cast<const uint4*>(Bfrag)
                          + (size_t)(blockIdx.y * 16) * 512;

    // W prefetch rings, depth 4, exec-masked loads
    // (explicit `if`, NOT ternary — r3: speculation doubled FETCH_SIZE)
    float wv0[4][4], wv1[4][4];
    #pragma unroll
    for (int p = 0; p < 4; ++p) {
        #pragma unroll
        for (int r = 0; r < 4; ++r) {
            float v0 = 0.0f, v1 = 0.0f;
            if (!msk0[r]) v0 = W[woff0[r] + p * 16];
            if (!msk1[r]) v1 = W[woff1[r] + p * 16];
            wv0[p][r] = v0;
            wv1[p][r] = v1;
        }
    }

    // stage: wave stages its 4 KB of tile T into buffer BUF (async, 4 chunks)
#define STAGE(T, BUF)                                                    \
    {                                                                    \
        const uint4* gs = bpanel + (T) * 512 + wave * 256 + lane;        \
        gload_lds16(gs,       &b_lds[BUF][wave * 256]);                  \
        gload_lds16(gs + 64,  &b_lds[BUF][wave * 256 + 64]);             \
        gload_lds16(gs + 128, &b_lds[BUF][wave * 256 + 128]);            \
        gload_lds16(gs + 192, &b_lds[BUF][wave * 256 + 192]);            \
    }

    STAGE(0, 0);
    __syncthreads();   // one-time full drain: tile 0 staged, prologue done

#define TILE_BODY(T, BUF, SLOT, PF, LAST)                                \
    {                                                                    \
        const int t_ = (T);                                              \
        /* copy current W slot to regs BEFORE the slot is re-prefetched */ \
        float wc0[4], wc1[4];                                            \
        _Pragma("unroll")                                                \
        for (int r = 0; r < 4; ++r) { wc0[r] = wv0[SLOT][r]; wc1[r] = wv1[SLOT][r]; } \
        if (PF) {                                                        \
            _Pragma("unroll")                                            \
            for (int r = 0; r < 4; ++r) {                                \
                float v0 = 0.0f, v1 = 0.0f;                              \
                if (!msk0[r]) v0 = W[woff0[r] + (t_ + 4) * 16];          \
                if (!msk1[r]) v1 = W[woff1[r] + (t_ + 4) * 16];          \
                wv0[SLOT][r] = v0;                                       \
                wv1[SLOT][r] = v1;                                       \
            }                                                            \
        }                                                                \
        if (!(LAST)) { STAGE(t_ + 1, 1 - (BUF)); }                       \
        /* pin: all loads above issue before everything below */         \
        __builtin_amdgcn_sched_barrier(0);                               \
        uint4 bb[8];                                                     \
        _Pragma("unroll")                                                \
        for (int s = 0; s < 8; ++s)                                      \
            bb[s] = b_lds[BUF][s * 64 + lane];                           \
        f32x4 acc00 = {0.f,0.f,0.f,0.f}, acc01 = {0.f,0.f,0.f,0.f};      \
        f32x4 acc10 = {0.f,0.f,0.f,0.f}, acc11 = {0.f,0.f,0.f,0.f};      \
        _Pragma("unroll")                                                \
        for (int s = 0; s < 4; ++s) {                                    \
            bf16x8 b0 = __builtin_bit_cast(bf16x8, bb[s]);               \
            bf16x8 b1 = __builtin_bit_cast(bf16x8, bb[s + 4]);           \
            acc00 = __builtin_amdgcn_mfma_f32_16x16x32_bf16(aA[s],     b0, acc00, 0, 0, 0); \
            acc01 = __builtin_amdgcn_mfma_f32_16x16x32_bf16(aA[s + 4], b1, acc01, 0, 0, 0); \
            acc10 = __builtin_amdgcn_mfma_f32_16x16x32_bf16(aB[s],     b0, acc10, 0, 0, 0); \
            acc11 = __builtin_amdgcn_mfma_f32_16x16x32_bf16(aB[s + 4], b1, acc11, 0, 0, 0); \
        }                                                                \
        _Pragma("unroll")                                                \
        for (int r = 0; r < 4; ++r) {                                    \
            float v0 = msk0[r] ? 0.0f : (acc00[r] + acc01[r] + wc0[r]);  \
            float v1 = msk1[r] ? 0.0f : (acc10[r] + acc11[r] + wc1[r]);  \
            out[ooff0[r] + t_ * 16] = v0;                                \
            out[ooff1[r] + t_ * 16] = v1;                                \
        }                                                                \
        if (!(LAST)) {                                                   \
            /* counted wait: the 8 stores above are the ONLY ops allowed \
               outstanding -> stage loads (issued before them) are done; \
               stores never block the barrier (T4). */                   \
            asm volatile("s_waitcnt vmcnt(8)" ::: "memory");             \
            __builtin_amdgcn_s_barrier();                                \
        }                                                                \
    }

    TILE_BODY(0,  0, 0, 1, 0);
    TILE_BODY(1,  1, 1, 1, 0);
    TILE_BODY(2,  0, 2, 1, 0);
    TILE_BODY(3,  1, 3, 1, 0);
    TILE_BODY(4,  0, 0, 1, 0);
    TILE_BODY(5,  1, 1, 1, 0);
    TILE_BODY(6,  0, 2, 1, 0);
    TILE_BODY(7,  1, 3, 1, 0);
    TILE_BODY(8,  0, 0, 1, 0);
    TILE_BODY(9,  1, 1, 1, 0);
    TILE_BODY(10, 0, 2, 1, 0);
    TILE_BODY(11, 1, 3, 1, 0);
    // peeled tail: no W prefetch (avoids OOB reads past the block's col range)
    TILE_BODY(12, 0, 0, 0, 0);
    TILE_BODY(13, 1, 1, 0, 0);
    TILE_BODY(14, 0, 2, 0, 0);
    TILE_BODY(15, 1, 3, 0, 1);
#undef TILE_BODY
#undef STAGE
}

extern "C" void kernel_launch(void* const* d_in, const int* in_sizes, int n_in,
                              void* d_out, int out_size, void* d_ws, size_t ws_size,
                              hipStream_t stream) {
    (void)in_sizes; (void)n_in; (void)out_size; (void)ws_size;

    const int*   x    = (const int*)d_in[0];
    const int*   mask = (const int*)d_in[1];
    const float* W    = (const float*)d_in[2];
    const float* A    = (const float*)d_in[3];
    const float* B    = (const float*)d_in[4];
    float*       out  = (float*)d_out;

    unsigned short* Abf   = (unsigned short*)d_ws;                       // 2 MiB
    unsigned short* Bfrag = (unsigned short*)((char*)d_ws + (2u << 20)); // 2 MiB

    prep_kernel<<<dim3(1536), dim3(256), 0, stream>>>(A, B, Abf, Bfrag);

    dim3 grid(NTOK / TPB, NCOL / CPB);   // (128, 16) = 2048 blocks
    emb_lora_mfma<<<grid, dim3(128), 0, stream>>>(x, mask, W, Abf, Bfrag, out);
}

// Round 19
// 50.068 us; speedup vs baseline: 1.2684x; 1.2684x over previous
//
#include <hip/hip_runtime.h>
#include <stdint.h>

#define NTOK 8192
#define NCOL 4096     // DIM == VOCAB
#define RANK 256
#define TPB  128      // tokens per block (4 waves x 32 tokens)
#define CPB  256      // cols per block (16 col-tiles)

typedef __attribute__((ext_vector_type(8))) short bf16x8;
typedef __attribute__((ext_vector_type(4))) float f32x4;

__device__ __forceinline__ unsigned short f2bf(float f) {
    unsigned int u = __float_as_uint(f);
    u += 0x7fffu + ((u >> 16) & 1u);   // RNE
    return (unsigned short)(u >> 16);
}

// async global->LDS, 16B per lane; LDS dest = uniform base + lane*16 (m104)
__device__ __forceinline__ void gload_lds16(const uint4* g, uint4* l) {
    __builtin_amdgcn_global_load_lds(
        (const __attribute__((address_space(1))) void*)g,
        (__attribute__((address_space(3))) void*)l, 16, 0, 0);
}

// ---- combined pre-pass ----
// blocks [0, 1024): A fp32 [4096][256] -> bf16 row-major (Abf, 2 MiB, L2-resident)
// blocks [1024, 1536): B fp32 [256][4096] -> bf16 MFMA-B-fragment order
//   frag layout: flat uint4 index = (ct*8 + ks)*64 + lane, 8 bf16 each:
//     element j = B[ks*32 + (lane>>4)*8 + j][ct*16 + (lane&15)]
__global__ __launch_bounds__(256) void prep_kernel(
    const float* __restrict__ A, const float* __restrict__ B,
    unsigned short* __restrict__ Abf, unsigned short* __restrict__ Bfrag)
{
    if (blockIdx.x < 1024) {
        int i = blockIdx.x * 256 + threadIdx.x;
        float4 v = reinterpret_cast<const float4*>(A)[i];
        ushort4 o;
        o.x = f2bf(v.x); o.y = f2bf(v.y); o.z = f2bf(v.z); o.w = f2bf(v.w);
        reinterpret_cast<ushort4*>(Abf)[i] = o;
    } else {
        int gt = (blockIdx.x - 1024) * 256 + threadIdx.x;
        int ct = gt >> 9;
        int rem = gt & 511;
        int ks = rem >> 6;
        int ln = rem & 63;
        int col = ct * 16 + (ln & 15);
        int kb  = ks * 32 + ((ln >> 4) << 3);
        unsigned short pk[8];
        #pragma unroll
        for (int j = 0; j < 8; ++j)
            pk[j] = f2bf(B[(size_t)(kb + j) * NCOL + col]);
        uint4 o;
        o.x = (unsigned)pk[0] | ((unsigned)pk[1] << 16);
        o.y = (unsigned)pk[2] | ((unsigned)pk[3] << 16);
        o.z = (unsigned)pk[4] | ((unsigned)pk[5] << 16);
        o.w = (unsigned)pk[6] | ((unsigned)pk[7] << 16);
        reinterpret_cast<uint4*>(Bfrag)[gt] = o;
    }
}

// ---- main: fused gather + LoRA GEMM + W add + mask ----
// r15 base (LDS-staged B, W-ring 4, counted vmcnt + raw barrier) + ONE
// change: B-stage pipeline deepened to lead-2 with 4 buffers. The stage
// issued in tile t is consumed in tile t+2, so the end-of-tile wait no
// longer requires this tile's own stage to land (true T4 "loads in flight
// across barriers"). Waits re-derived per tile:
//   steady: newer-than-(t-1)'s-stage = 8 stores(t-1) + 8 Wpref + 2 stage +
//           8 stores = vmcnt(26); tails 18/18/16.
__global__ __launch_bounds__(256) void emb_lora_mfma(
    const int* __restrict__ x,
    const int* __restrict__ mask,
    const float* __restrict__ W,
    const unsigned short* __restrict__ Abf,
    const unsigned short* __restrict__ Bfrag,
    float* __restrict__ out)
{
    __shared__ int s_idx[TPB];
    __shared__ int s_msk[TPB];
    __shared__ uint4 b_lds[4][512];   // 4 x 8 KB (tile T lives in buf T&3)

    const int tid  = threadIdx.x;
    const int lane = tid & 63;
    const int wave = tid >> 6;        // wave owns tokens [wave*32, wave*32+32)
    const int tok0 = blockIdx.x * TPB;
    const int col0 = blockIdx.y * CPB;

    if (tid < TPB) {
        s_idx[tid] = x[tok0 + tid];
        s_msk[tid] = mask[tok0 + tid];
    }
    __syncthreads();

    // A fragments for both token groups (A-operand row = lane&15)
    const int a0row = s_idx[wave * 32 + (lane & 15)];
    const int a1row = s_idx[wave * 32 + 16 + (lane & 15)];
    const unsigned short* ap0 = Abf + (size_t)a0row * RANK + ((lane >> 4) << 3);
    const unsigned short* ap1 = Abf + (size_t)a1row * RANK + ((lane >> 4) << 3);
    bf16x8 aA[8], aB[8];
    #pragma unroll
    for (int s = 0; s < 8; ++s) {
        aA[s] = *reinterpret_cast<const bf16x8*>(ap0 + s * 32);
        aB[s] = *reinterpret_cast<const bf16x8*>(ap1 + s * 32);
    }

    // per-thread epilogue state: group g covers rows wave*32+g*16+(lane>>4)*4+r
    const int colb = col0 + (lane & 15);
    int msk0[4], msk1[4];
    unsigned woff0[4], woff1[4], ooff0[4], ooff1[4];
    #pragma unroll
    for (int r = 0; r < 4; ++r) {
        int row0 = wave * 32 + ((lane >> 4) << 2) + r;
        int row1 = row0 + 16;
        msk0[r] = s_msk[row0];
        msk1[r] = s_msk[row1];
        woff0[r] = (unsigned)s_idx[row0] * NCOL + colb;
        woff1[r] = (unsigned)s_idx[row1] * NCOL + colb;
        ooff0[r] = (unsigned)(tok0 + row0) * NCOL + colb;
        ooff1[r] = (unsigned)(tok0 + row1) * NCOL + colb;
    }

    // block's 16 col-tiles start at global col-tile blockIdx.y*16
    const uint4* bpanel = reinterpret_cast<const uint4*>(Bfrag)
                          + (size_t)(blockIdx.y * 16) * 512;

    // W prefetch rings, depth 4, exec-masked loads
    // (explicit `if`, NOT ternary — r3: speculation doubled FETCH_SIZE)
    float wv0[4][4], wv1[4][4];
    #pragma unroll
    for (int p = 0; p < 4; ++p) {
        #pragma unroll
        for (int r = 0; r < 4; ++r) {
            float v0 = 0.0f, v1 = 0.0f;
            if (!msk0[r]) v0 = W[woff0[r] + p * 16];
            if (!msk1[r]) v1 = W[woff1[r] + p * 16];
            wv0[p][r] = v0;
            wv1[p][r] = v1;
        }
    }

    // stage: wave stages its 2 KB of tile T into buffer T&3 (async)
#define STAGE(T)                                                         \
    {                                                                    \
        const uint4* gs = bpanel + (T) * 512 + wave * 128 + lane;        \
        gload_lds16(gs,      &b_lds[(T) & 3][wave * 128]);               \
        gload_lds16(gs + 64, &b_lds[(T) & 3][wave * 128 + 64]);          \
    }

    STAGE(0);
    STAGE(1);
    __syncthreads();   // one-time full drain: tiles 0,1 staged

#define TILE_BODY(T, SLOT, PF, STG, WC, LAST)                            \
    {                                                                    \
        const int t_ = (T);                                              \
        /* copy current W slot to regs BEFORE the slot is re-prefetched */ \
        float wc0[4], wc1[4];                                            \
        _Pragma("unroll")                                                \
        for (int r = 0; r < 4; ++r) { wc0[r] = wv0[SLOT][r]; wc1[r] = wv1[SLOT][r]; } \
        if (PF) {                                                        \
            _Pragma("unroll")                                            \
            for (int r = 0; r < 4; ++r) {                                \
                float v0 = 0.0f, v1 = 0.0f;                              \
                if (!msk0[r]) v0 = W[woff0[r] + (t_ + 4) * 16];          \
                if (!msk1[r]) v1 = W[woff1[r] + (t_ + 4) * 16];          \
                wv0[SLOT][r] = v0;                                       \
                wv1[SLOT][r] = v1;                                       \
            }                                                            \
        }                                                                \
        if (STG) { STAGE(t_ + 2); }                                      \
        /* pin: all loads above issue before everything below */         \
        __builtin_amdgcn_sched_barrier(0);                               \
        uint4 bb[8];                                                     \
        _Pragma("unroll")                                                \
        for (int s = 0; s < 8; ++s)                                      \
            bb[s] = b_lds[t_ & 3][s * 64 + lane];                        \
        f32x4 acc00 = {0.f,0.f,0.f,0.f}, acc01 = {0.f,0.f,0.f,0.f};      \
        f32x4 acc10 = {0.f,0.f,0.f,0.f}, acc11 = {0.f,0.f,0.f,0.f};      \
        _Pragma("unroll")                                                \
        for (int s = 0; s < 4; ++s) {                                    \
            bf16x8 b0 = __builtin_bit_cast(bf16x8, bb[s]);               \
            bf16x8 b1 = __builtin_bit_cast(bf16x8, bb[s + 4]);           \
            acc00 = __builtin_amdgcn_mfma_f32_16x16x32_bf16(aA[s],     b0, acc00, 0, 0, 0); \
            acc01 = __builtin_amdgcn_mfma_f32_16x16x32_bf16(aA[s + 4], b1, acc01, 0, 0, 0); \
            acc10 = __builtin_amdgcn_mfma_f32_16x16x32_bf16(aB[s],     b0, acc10, 0, 0, 0); \
            acc11 = __builtin_amdgcn_mfma_f32_16x16x32_bf16(aB[s + 4], b1, acc11, 0, 0, 0); \
        }                                                                \
        _Pragma("unroll")                                                \
        for (int r = 0; r < 4; ++r) {                                    \
            float v0 = msk0[r] ? 0.0f : (acc00[r] + acc01[r] + wc0[r]);  \
            float v1 = msk1[r] ? 0.0f : (acc10[r] + acc11[r] + wc1[r]);  \
            out[ooff0[r] + t_ * 16] = v0;                                \
            out[ooff1[r] + t_ * 16] = v1;                                \
        }                                                                \
        if (!(LAST)) {                                                   \
            /* counted wait, lead-2 pipeline: guarantees the stage for    \
               tile t+1 (issued at t-1) retired, while THIS tile's stage  \
               + Wpref + stores stay in flight. */                        \
            asm volatile("s_waitcnt vmcnt(" #WC ")" ::: "memory");       \
            __builtin_amdgcn_s_barrier();                                \
        }                                                                \
    }

    TILE_BODY(0,  0, 1, 1, 26, 0);
    TILE_BODY(1,  1, 1, 1, 26, 0);
    TILE_BODY(2,  2, 1, 1, 26, 0);
    TILE_BODY(3,  3, 1, 1, 26, 0);
    TILE_BODY(4,  0, 1, 1, 26, 0);
    TILE_BODY(5,  1, 1, 1, 26, 0);
    TILE_BODY(6,  2, 1, 1, 26, 0);
    TILE_BODY(7,  3, 1, 1, 26, 0);
    TILE_BODY(8,  0, 1, 1, 26, 0);
    TILE_BODY(9,  1, 1, 1, 26, 0);
    TILE_BODY(10, 2, 1, 1, 26, 0);
    TILE_BODY(11, 3, 1, 1, 26, 0);
    // tail: no W prefetch (t=12..15), no stage (t=14,15); waits re-derived
    TILE_BODY(12, 0, 0, 1, 18, 0);
    TILE_BODY(13, 1, 0, 1, 18, 0);
    TILE_BODY(14, 2, 0, 0, 16, 0);
    TILE_BODY(15, 3, 0, 0, 16, 1);
#undef TILE_BODY
#undef STAGE
}

extern "C" void kernel_launch(void* const* d_in, const int* in_sizes, int n_in,
                              void* d_out, int out_size, void* d_ws, size_t ws_size,
                              hipStream_t stream) {
    (void)in_sizes; (void)n_in; (void)out_size; (void)ws_size;

    const int*   x    = (const int*)d_in[0];
    const int*   mask = (const int*)d_in[1];
    const float* W    = (const float*)d_in[2];
    const float* A    = (const float*)d_in[3];
    const float* B    = (const float*)d_in[4];
    float*       out  = (float*)d_out;

    unsigned short* Abf   = (unsigned short*)d_ws;                       // 2 MiB
    unsigned short* Bfrag = (unsigned short*)((char*)d_ws + (2u << 20)); // 2 MiB

    prep_kernel<<<dim3(1536), dim3(256), 0, stream>>>(A, B, Abf, Bfrag);

    dim3 grid(NTOK / TPB, NCOL / CPB);   // (64, 16) = 1024 blocks
    emb_lora_mfma<<<grid, dim3(256), 0, stream>>>(x, mask, W, Abf, Bfrag, out);
}